// Round 2
// baseline (126.302 us; speedup 1.0000x reference)
//
#include <hip/hip_runtime.h>
#include <hip/hip_fp16.h>

#define DEG 32
#define K_KNOTS 7
#define NINT 6   // K-1 intervals
#define CAP 96   // src-bucket capacity; multiplicity ~ Poisson(32), P(>96) ~ 0

typedef _Float16 half_t;
typedef _Float16 h2 __attribute__((ext_vector_type(2)));

// 8-byte packed edge record: unit vector (fp16 x3) + f-spline value (fp16),
// stored as two half2: (x,y) and (z,f). 320k edges * 8 B = 2.56 MB stays
// L2-resident for the node-centric phase-2 gathers.
union UF8 {
    uint2 u;
    struct { h2 xy; h2 zf; } h;
};

__device__ inline float fdot2(h2 a, h2 b, float c) {
#if __has_builtin(__builtin_amdgcn_fdot2)
    return __builtin_amdgcn_fdot2(a, b, c, false);
#else
    return (float)a.x * (float)b.x + (float)a.y * (float)b.y + c;
#endif
}

// Natural cubic spline with uniform knot spacing h. y[7] -> C[6] = (a,b,c,d).
// Mirrors reference: tridiag(main=4h, off=h) solve for interior 2nd derivs.
__device__ inline void spline_coeffs(const float* __restrict__ y, float h, float4* C) {
    float dy[NINT];
#pragma unroll
    for (int i = 0; i < NINT; ++i) dy[i] = (y[i + 1] - y[i]) / h;
    float rhs[5];
#pragma unroll
    for (int i = 0; i < 5; ++i) rhs[i] = 6.0f * (dy[i + 1] - dy[i]);
    // Thomas algorithm, n=5, diag=4h, off=h
    float cp[5], dp[5];
    float denom = 4.0f * h;
    cp[0] = h / denom;
    dp[0] = rhs[0] / denom;
#pragma unroll
    for (int i = 1; i < 5; ++i) {
        denom = 4.0f * h - h * cp[i - 1];
        cp[i] = h / denom;
        dp[i] = (rhs[i] - h * dp[i - 1]) / denom;
    }
    float M[K_KNOTS];
    M[0] = 0.0f; M[6] = 0.0f;
    M[5] = dp[4];
#pragma unroll
    for (int i = 3; i >= 0; --i) M[i + 1] = dp[i] - cp[i] * M[i + 2];
#pragma unroll
    for (int i = 0; i < NINT; ++i) {
        C[i].x = y[i];
        C[i].y = dy[i] - h * (2.0f * M[i] + M[i + 1]) * (1.0f / 6.0f);
        C[i].z = M[i] * 0.5f;
        C[i].w = (M[i + 1] - M[i]) / (6.0f * h);
    }
}

// Zero the per-node bucket counters (ws is poisoned every iteration).
__global__ __launch_bounds__(256) void zero_cnt(int* __restrict__ cnt, int N) {
    int i = blockIdx.x * blockDim.x + threadIdx.x;
    if (i < N) cnt[i] = 0;
}

// Phase 1: per-edge. l = |r_e|, u_e = r_e/l, f_e = f(l); pack to 8 B.
// Additionally buckets edge e under node src[e] (rank via atomicAdd) so
// phase 2 can iterate members per node. Rank order is irrelevant (sum).
__global__ __launch_bounds__(256) void edge_kernel(
    const float* __restrict__ r, const float* __restrict__ fc,
    const int* __restrict__ src,
    uint2* __restrict__ uf, int* __restrict__ cnt, int* __restrict__ perm,
    int E) {
    __shared__ float4 sF[NINT];
    if (threadIdx.x == 0) {
        float4 c[NINT];
        spline_coeffs(fc, 8.0f / 6.0f, c);  // radial knots linspace(0,8,7)
#pragma unroll
        for (int i = 0; i < NINT; ++i) sF[i] = c[i];
    }
    __syncthreads();
    int e = blockIdx.x * blockDim.x + threadIdx.x;
    if (e >= E) return;
    float x = r[3 * e + 0];
    float y = r[3 * e + 1];
    float z = r[3 * e + 2];
    float d = x * x + y * y + z * z;
    float rl = rsqrtf(d);
    float l = d * rl;          // |r|
    // f(l): l >= 0 so trunc == floor; idx clamp handles extrapolation (l > 8)
    float u = l * (6.0f / 8.0f);
    int idx = (int)u;
    idx = idx < 0 ? 0 : (idx > NINT - 1 ? NINT - 1 : idx);
    float s = l - (8.0f / 6.0f) * (float)idx;
    float4 c = sF[idx];
    float f = c.x + s * (c.y + s * (c.z + s * c.w));
    UF8 q;
    q.h.xy.x = (half_t)(x * rl);
    q.h.xy.y = (half_t)(y * rl);
    q.h.zf.x = (half_t)(z * rl);
    q.h.zf.y = (half_t)f;
    uf[e] = q.u;

    int a = src[e];
    int rank = atomicAdd(&cnt[a], 1);
    if (rank < CAP) perm[a * CAP + rank] = e;
}

// Phase 2, node-centric (R5): one WAVE per node a. The 32-record neighbor
// block (= dst-block of node a) is loaded ONCE, coalesced, and kept in
// registers: lane layout = (half, j) with j = lane&31 the neighbor index,
// half = lane>>5 selecting one of two member edges per pass. Previously the
// block was re-gathered by every edge with src==a (~32x redundancy, 123 MB
// of 16-scattered-line loads); now it's 10k x 384 B coalesced + ~12 B per
// member. Per pass: 2 member edges e, each lane computes one triplet
// f_j * g(dot(u_j, -u_e)) * [src_j != dst_e], 5-round shfl_xor reduce
// within each 32-lane half, lane j==0 writes out[e] = f_e * sum.
__global__ __launch_bounds__(256) void node_kernel(
    const uint2* __restrict__ uf, const float* __restrict__ gc,
    const int* __restrict__ src, const int* __restrict__ dst,
    const int* __restrict__ cnt, const int* __restrict__ perm,
    float* __restrict__ out, int N) {
    __shared__ float4 sG[NINT];
    if (threadIdx.x == 0) {
        float4 c[NINT];
        spline_coeffs(gc, 2.0f / 6.0f, c);  // angular knots linspace(-1,1,7)
#pragma unroll
        for (int i = 0; i < NINT; ++i) sG[i] = c[i];
    }
    __syncthreads();

    int a = (blockIdx.x * blockDim.x + threadIdx.x) >> 6;  // one wave = one node
    int lane = threadIdx.x & 63;
    if (a >= N) return;  // no further __syncthreads below

    int j = lane & 31;     // neighbor slot
    int half = lane >> 5;  // which member edge this pass

    // Neighbor j of node a: record + its src (for the mask). Lanes j and
    // j+32 load the same address -> 4 cache lines total, L1 broadcast.
    UF8 nk; nk.u = uf[(size_t)a * DEG + j];
    int sj = src[(size_t)a * DEG + j];
    h2 kxy = nk.h.xy;
    h2 kz0; kz0.x = nk.h.zf.x; kz0.y = (half_t)0.0f;
    float fj = (float)nk.h.zf.y;

    int m = cnt[a];
    m = m > CAP ? CAP : m;

    for (int base = 0; base < m; base += 2) {
        int mm = base + half;
        bool live = mm < m;
        int e = 0;
        if (live) e = perm[a * CAP + mm];   // guarded: perm slot mm<m is valid
        UF8 qe; qe.u = uf[e];
        int de = dst[e];
        // cos = dot(u_j, -u_e): negate e-side unit vector via sign-bit XOR
        uint2 neg = qe.u;
        neg.x ^= 0x80008000u;   // -(x,y)
        neg.y ^= 0x00008000u;   // -(z), keep f
        h2 ne_xy = __builtin_bit_cast(h2, neg.x);
        h2 ne_zf = __builtin_bit_cast(h2, neg.y);  // (-z, f)
        float fe = (float)qe.h.zf.y;

        float cosv = fdot2(kxy, ne_xy, fdot2(kz0, ne_zf, 0.0f));  // kz*(-z)+0*f
        cosv = fminf(fmaxf(cosv, -1.0f), 1.0f);
        // g(cos): cos in [-1,1] -> u in [0,6]; trunc == floor (u >= 0)
        float u = (cosv + 1.0f) * 3.0f;
        int idx = (int)u;
        idx = idx > NINT - 1 ? NINT - 1 : idx;
        float s = cosv - (-1.0f + (2.0f / 6.0f) * (float)idx);
        float4 c = sG[idx];
        float g = c.x + s * (c.y + s * (c.z + s * c.w));

        float term = (live && (sj != de)) ? fj * g : 0.0f;
        // reduce 32 lanes within each half (xor masks < 32 stay in-half)
        term += __shfl_xor(term, 1, 64);
        term += __shfl_xor(term, 2, 64);
        term += __shfl_xor(term, 4, 64);
        term += __shfl_xor(term, 8, 64);
        term += __shfl_xor(term, 16, 64);
        if (live && j == 0) out[e] = fe * term;
    }
}

extern "C" void kernel_launch(void* const* d_in, const int* in_sizes, int n_in,
                              void* d_out, int out_size, void* d_ws, size_t ws_size,
                              hipStream_t stream) {
    const float* r   = (const float*)d_in[0];
    const float* fc  = (const float*)d_in[1];
    const float* gc  = (const float*)d_in[2];
    const int* src   = (const int*)d_in[3];
    const int* dst   = (const int*)d_in[4];
    float* out = (float*)d_out;
    int E = in_sizes[3];
    int N = E / DEG;

    // ws layout: uf (E*8 B) | cnt (N*4 B) | perm (N*CAP*4 B)  -> ~6.5 MB
    uint2* uf = (uint2*)d_ws;
    int* cnt  = (int*)((char*)d_ws + (size_t)E * 8);
    int* perm = cnt + N;

    int threads = 256;
    zero_cnt<<<(N + threads - 1) / threads, threads, 0, stream>>>(cnt, N);
    edge_kernel<<<(E + threads - 1) / threads, threads, 0, stream>>>(
        r, fc, src, uf, cnt, perm, E);
    long long T2 = (long long)N * 64;   // one wave per node
    int blocks2 = (int)((T2 + threads - 1) / threads);
    node_kernel<<<blocks2, threads, 0, stream>>>(
        uf, gc, src, dst, cnt, perm, out, N);
}

// Round 3
// 108.942 us; speedup vs baseline: 1.1594x; 1.1594x over previous
//
#include <hip/hip_runtime.h>
#include <hip/hip_fp16.h>

#define DEG 32
#define K_KNOTS 7
#define NINT 6   // K-1 intervals
#define CAP 96   // src-bucket capacity; multiplicity ~ Poisson(32), P(>96) ~ 0
#define NPB 4    // nodes (waves) per block

typedef _Float16 half_t;
typedef _Float16 h2 __attribute__((ext_vector_type(2)));

// 8-byte packed edge record: unit vector (fp16 x3) + f-spline value (fp16),
// stored as two half2: (x,y) and (z,f). 320k edges * 8 B = 2.56 MB stays
// L2-resident for the phase-2 member gathers.
union UF8 {
    uint2 u;
    struct { h2 xy; h2 zf; } h;
};

__device__ inline float fdot2(h2 a, h2 b, float c) {
#if __has_builtin(__builtin_amdgcn_fdot2)
    return __builtin_amdgcn_fdot2(a, b, c, false);
#else
    return (float)a.x * (float)b.x + (float)a.y * (float)b.y + c;
#endif
}

// Natural cubic spline with uniform knot spacing h. y[7] -> C[6] = (a,b,c,d).
// Mirrors reference: tridiag(main=4h, off=h) solve for interior 2nd derivs.
__device__ inline void spline_coeffs(const float* __restrict__ y, float h, float4* C) {
    float dy[NINT];
#pragma unroll
    for (int i = 0; i < NINT; ++i) dy[i] = (y[i + 1] - y[i]) / h;
    float rhs[5];
#pragma unroll
    for (int i = 0; i < 5; ++i) rhs[i] = 6.0f * (dy[i + 1] - dy[i]);
    // Thomas algorithm, n=5, diag=4h, off=h
    float cp[5], dp[5];
    float denom = 4.0f * h;
    cp[0] = h / denom;
    dp[0] = rhs[0] / denom;
#pragma unroll
    for (int i = 1; i < 5; ++i) {
        denom = 4.0f * h - h * cp[i - 1];
        cp[i] = h / denom;
        dp[i] = (rhs[i] - h * dp[i - 1]) / denom;
    }
    float M[K_KNOTS];
    M[0] = 0.0f; M[6] = 0.0f;
    M[5] = dp[4];
#pragma unroll
    for (int i = 3; i >= 0; --i) M[i + 1] = dp[i] - cp[i] * M[i + 2];
#pragma unroll
    for (int i = 0; i < NINT; ++i) {
        C[i].x = y[i];
        C[i].y = dy[i] - h * (2.0f * M[i] + M[i + 1]) * (1.0f / 6.0f);
        C[i].z = M[i] * 0.5f;
        C[i].w = (M[i + 1] - M[i]) / (6.0f * h);
    }
}

// Zero the per-node bucket counters (ws is poisoned every iteration).
__global__ __launch_bounds__(256) void zero_cnt(int* __restrict__ cnt, int N) {
    int i = blockIdx.x * blockDim.x + threadIdx.x;
    if (i < N) cnt[i] = 0;
}

// Phase 1: per-edge. l = |r_e|, u_e = r_e/l, f_e = f(l); pack to 8 B.
// Additionally buckets edge e under node src[e] (rank via atomicAdd) so
// phase 2 can iterate members per node. Rank order is irrelevant (sum).
__global__ __launch_bounds__(256) void edge_kernel(
    const float* __restrict__ r, const float* __restrict__ fc,
    const int* __restrict__ src,
    uint2* __restrict__ uf, int* __restrict__ cnt, int* __restrict__ perm,
    int E) {
    __shared__ float4 sF[NINT];
    if (threadIdx.x == 0) {
        float4 c[NINT];
        spline_coeffs(fc, 8.0f / 6.0f, c);  // radial knots linspace(0,8,7)
#pragma unroll
        for (int i = 0; i < NINT; ++i) sF[i] = c[i];
    }
    __syncthreads();
    int e = blockIdx.x * blockDim.x + threadIdx.x;
    if (e >= E) return;
    float x = r[3 * e + 0];
    float y = r[3 * e + 1];
    float z = r[3 * e + 2];
    float d = x * x + y * y + z * z;
    float rl = rsqrtf(d);
    float l = d * rl;          // |r|
    // f(l): l >= 0 so trunc == floor; idx clamp handles extrapolation (l > 8)
    float u = l * (6.0f / 8.0f);
    int idx = (int)u;
    idx = idx < 0 ? 0 : (idx > NINT - 1 ? NINT - 1 : idx);
    float s = l - (8.0f / 6.0f) * (float)idx;
    float4 c = sF[idx];
    float f = c.x + s * (c.y + s * (c.z + s * c.w));
    UF8 q;
    q.h.xy.x = (half_t)(x * rl);
    q.h.xy.y = (half_t)(y * rl);
    q.h.zf.x = (half_t)(z * rl);
    q.h.zf.y = (half_t)f;
    uf[e] = q.u;

    int a = src[e];
    int rank = atomicAdd(&cnt[a], 1);
    if (rank < CAP) perm[a * CAP + rank] = e;
}

// Phase 2, node-centric R6 (R5 post-mortem: 2-edges-per-pass + 5-round shfl
// reduce serialized the wave -> +44 us). Now: one wave per node a; the 32
// neighbor records (+ their src) are staged in LDS ONCE (coalesced 384 B),
// then LANE = MEMBER EDGE: each lane owns one output edge e with src[e]==a
// (avg multiplicity = 32 ~ lane count), gathers its own 12 B of member data
// (the only scattered traffic left: 320k x 12 B vs R1's 10.24M redundant
// gathers), and serially accumulates over the 32 neighbors via broadcast
// LDS reads (same addr for all lanes -> conflict-free). No cross-lane ops,
// private accumulator, direct out[e] store.
__global__ __launch_bounds__(256) void node_kernel(
    const uint2* __restrict__ uf, const float* __restrict__ gc,
    const int* __restrict__ src, const int* __restrict__ dst,
    const int* __restrict__ cnt, const int* __restrict__ perm,
    float* __restrict__ out, int N) {
    __shared__ float4 sG[NINT];
    __shared__ uint2 sRec[NPB][DEG];  // 1 KB: packed neighbor records
    __shared__ int   sSrc[NPB][DEG];  // 512 B: neighbor src ids (mask test)

    if (threadIdx.x == 0) {
        float4 c[NINT];
        spline_coeffs(gc, 2.0f / 6.0f, c);  // angular knots linspace(-1,1,7)
#pragma unroll
        for (int i = 0; i < NINT; ++i) sG[i] = c[i];
    }

    int wid = threadIdx.x >> 6;   // wave slot = node slot
    int lane = threadIdx.x & 63;
    int a = blockIdx.x * NPB + wid;
    bool na = a < N;

    // Stage node a's neighbor block: lanes 0-31 the 8 B records (256 B
    // coalesced), lanes 32-63 the src ids (128 B coalesced).
    if (na) {
        int j = lane & 31;
        if (lane < 32) sRec[wid][j] = uf[(size_t)a * DEG + j];
        else           sSrc[wid][j] = src[(size_t)a * DEG + j];
    }
    __syncthreads();
    if (!na) return;

    int m = cnt[a];
    m = m > CAP ? CAP : m;

    for (int mm = lane; mm < m; mm += 64) {
        int e = perm[a * CAP + mm];   // member edge owned by this lane
        UF8 qe; qe.u = uf[e];         // scattered 8 B gather (L2-resident)
        int de = dst[e];              // scattered 4 B gather
        // cos = dot(u_j, -u_e): negate e-side unit vector via sign-bit XOR
        uint2 neg = qe.u;
        neg.x ^= 0x80008000u;         // -(x,y)
        neg.y ^= 0x00008000u;         // -(z), keep f
        h2 ne_xy = __builtin_bit_cast(h2, neg.x);
        h2 ne_zf = __builtin_bit_cast(h2, neg.y);   // (-z, f)
        float fe = (float)qe.h.zf.y;

        float acc = 0.0f;
#pragma unroll 8
        for (int j = 0; j < DEG; ++j) {
            uint2 kk = sRec[wid][j];     // broadcast LDS read
            int sj = sSrc[wid][j];       // broadcast LDS read
            h2 kxy = __builtin_bit_cast(h2, kk.x);
            h2 kz0 = __builtin_bit_cast(h2, kk.y & 0x0000FFFFu);  // (z, +0)
            float fj = (float)__builtin_bit_cast(h2, kk.y).y;
            float cosv = fdot2(kxy, ne_xy, fdot2(kz0, ne_zf, 0.0f));
            cosv = fminf(fmaxf(cosv, -1.0f), 1.0f);
            // g(cos): cos in [-1,1] -> u in [0,6]; trunc == floor (u >= 0)
            float u = (cosv + 1.0f) * 3.0f;
            int idx = (int)u;
            idx = idx > NINT - 1 ? NINT - 1 : idx;
            float s = cosv - (-1.0f + (2.0f / 6.0f) * (float)idx);
            float4 c = sG[idx];
            float g = c.x + s * (c.y + s * (c.z + s * c.w));
            float term = (sj != de) ? fj * g : 0.0f;
            acc += term;
        }
        out[e] = fe * acc;   // scattered 4 B store, once per edge
    }
}

extern "C" void kernel_launch(void* const* d_in, const int* in_sizes, int n_in,
                              void* d_out, int out_size, void* d_ws, size_t ws_size,
                              hipStream_t stream) {
    const float* r   = (const float*)d_in[0];
    const float* fc  = (const float*)d_in[1];
    const float* gc  = (const float*)d_in[2];
    const int* src   = (const int*)d_in[3];
    const int* dst   = (const int*)d_in[4];
    float* out = (float*)d_out;
    int E = in_sizes[3];
    int N = E / DEG;

    // ws layout: uf (E*8 B) | cnt (N*4 B) | perm (N*CAP*4 B)  -> ~6.5 MB
    uint2* uf = (uint2*)d_ws;
    int* cnt  = (int*)((char*)d_ws + (size_t)E * 8);
    int* perm = cnt + N;

    int threads = 256;
    zero_cnt<<<(N + threads - 1) / threads, threads, 0, stream>>>(cnt, N);
    edge_kernel<<<(E + threads - 1) / threads, threads, 0, stream>>>(
        r, fc, src, uf, cnt, perm, E);
    int blocks2 = (N + NPB - 1) / NPB;   // one wave per node
    node_kernel<<<blocks2, threads, 0, stream>>>(
        uf, gc, src, dst, cnt, perm, out, N);
}

// Round 4
// 81.654 us; speedup vs baseline: 1.5468x; 1.3342x over previous
//
#include <hip/hip_runtime.h>
#include <hip/hip_fp16.h>

#define DEG 32
#define K_KNOTS 7
#define NINT 6  // K-1 intervals

typedef _Float16 half_t;
typedef _Float16 h2 __attribute__((ext_vector_type(2)));

// 8-byte packed edge record: unit vector (fp16 x3) + f-spline value (fp16),
// stored as two half2: (x,y) and (z,f). 320k edges * 8 B = 2.56 MB keeps the
// phase-2 random gather L2-resident (R3/R4: FETCH ~19 MB).
union UF8 {
    uint2 u;
    struct { h2 xy; h2 zf; } h;
};

__device__ inline float fdot2(h2 a, h2 b, float c) {
#if __has_builtin(__builtin_amdgcn_fdot2)
    return __builtin_amdgcn_fdot2(a, b, c, false);
#else
    return (float)a.x * (float)b.x + (float)a.y * (float)b.y + c;
#endif
}

// Natural cubic spline with uniform knot spacing h. y[7] -> C[6] = (a,b,c,d).
// Mirrors reference: tridiag(main=4h, off=h) solve for interior 2nd derivs.
__device__ inline void spline_coeffs(const float* __restrict__ y, float h, float4* C) {
    float dy[NINT];
#pragma unroll
    for (int i = 0; i < NINT; ++i) dy[i] = (y[i + 1] - y[i]) / h;
    float rhs[5];
#pragma unroll
    for (int i = 0; i < 5; ++i) rhs[i] = 6.0f * (dy[i + 1] - dy[i]);
    // Thomas algorithm, n=5, diag=4h, off=h
    float cp[5], dp[5];
    float denom = 4.0f * h;
    cp[0] = h / denom;
    dp[0] = rhs[0] / denom;
#pragma unroll
    for (int i = 1; i < 5; ++i) {
        denom = 4.0f * h - h * cp[i - 1];
        cp[i] = h / denom;
        dp[i] = (rhs[i] - h * dp[i - 1]) / denom;
    }
    float M[K_KNOTS];
    M[0] = 0.0f; M[6] = 0.0f;
    M[5] = dp[4];
#pragma unroll
    for (int i = 3; i >= 0; --i) M[i + 1] = dp[i] - cp[i] * M[i + 2];
#pragma unroll
    for (int i = 0; i < NINT; ++i) {
        C[i].x = y[i];
        C[i].y = dy[i] - h * (2.0f * M[i] + M[i + 1]) * (1.0f / 6.0f);
        C[i].z = M[i] * 0.5f;
        C[i].w = (M[i + 1] - M[i]) / (6.0f * h);
    }
}

// Phase 1: per-edge. l = |r_e|, u_e = r_e/l, f_e = f(l); pack to 8 B.
__global__ __launch_bounds__(256) void edge_kernel(
    const float* __restrict__ r, const float* __restrict__ fc,
    uint2* __restrict__ uf, int E) {
    __shared__ float4 sF[NINT];
    if (threadIdx.x == 0) {
        float4 c[NINT];
        spline_coeffs(fc, 8.0f / 6.0f, c);  // radial knots linspace(0,8,7)
#pragma unroll
        for (int i = 0; i < NINT; ++i) sF[i] = c[i];
    }
    __syncthreads();
    int e = blockIdx.x * blockDim.x + threadIdx.x;
    if (e >= E) return;
    float x = r[3 * e + 0];
    float y = r[3 * e + 1];
    float z = r[3 * e + 2];
    float d = x * x + y * y + z * z;
    float rl = rsqrtf(d);
    float l = d * rl;          // |r|
    // f(l): l >= 0 so trunc == floor; idx clamp handles extrapolation (l > 8)
    float u = l * (6.0f / 8.0f);
    int idx = (int)u;
    idx = idx < 0 ? 0 : (idx > NINT - 1 ? NINT - 1 : idx);
    float s = l - (8.0f / 6.0f) * (float)idx;
    float4 c = sF[idx];
    float f = c.x + s * (c.y + s * (c.z + s * c.w));
    UF8 q;
    q.h.xy.x = (half_t)(x * rl);
    q.h.xy.y = (half_t)(y * rl);
    q.h.zf.x = (half_t)(z * rl);
    q.h.zf.y = (half_t)f;
    uf[e] = q.u;
}

// Phase 2: FOUR lanes per edge (R4 post-mortem: thread-per-edge made every
// vector load 64 scattered cache lines -> TA/L1 serialization; R3's 32-lane
// layout paid 10 shfl-instr/triplet; R5/R6 node-centric bucket rebuild cost
// more than the gather redundancy it removed -> reverted). Lane group q=0..3
// of edge e loads 64 B of the 256 B neighbor block -> for a fixed unroll slot
// the 4 lanes cover one contiguous cache line, each lane serially accumulates
// its 8 triplets, then a 2-round shfl reduces the group.
// R7 change vs R1: dst[e] is deterministic in this problem
// (dst = repeat(arange(N), DEG) -> dst[e] = e >> 5), so the per-group
// scattered dst gather is replaced by a shift and the dst stream dropped.
__global__ __launch_bounds__(256) void triplet_kernel(
    const uint2* __restrict__ uf, const float* __restrict__ gc,
    const int* __restrict__ src,
    float* __restrict__ out, int E) {
    __shared__ float4 sG[NINT];
    if (threadIdx.x == 0) {
        float4 c[NINT];
        spline_coeffs(gc, 2.0f / 6.0f, c);  // angular knots linspace(-1,1,7)
#pragma unroll
        for (int i = 0; i < NINT; ++i) sG[i] = c[i];
    }
    __syncthreads();

    int t = blockIdx.x * blockDim.x + threadIdx.x;
    int e = t >> 2;          // 4 consecutive lanes share one edge
    int q = t & 3;           // lane's slice of the neighbor block
    if (e >= E) return;

    int a = src[e];          // same addr for the 4 group lanes
    int de = e >> 5;         // dst[e] = e / DEG by construction
    UF8 qe; qe.u = uf[e];
    // negated e-side unit vector, once: cos = dot(u_k, -u_e)
    uint2 neg = qe.u;
    neg.x ^= 0x80008000u;    // -(x,y)
    neg.y ^= 0x00008000u;    // -(z), keep f
    h2 ne_xy = __builtin_bit_cast(h2, neg.x);
    h2 ne_zf = __builtin_bit_cast(h2, neg.y);
    h2 ne_z0; ne_z0.x = ne_zf.x; ne_z0.y = (half_t)0.0f;
    float fe = (float)qe.h.zf.y;

    // lane's 8 records: uint4 slot it covers records q*8+2it, q*8+2it+1;
    // 4 lanes at slot it = contiguous 64 B.
    const uint4* blk = (const uint4*)(uf + (size_t)a * DEG);
    const int4* sblk = (const int4*)(src + (size_t)a * DEG);
    uint4 rq[4];
    int4 sq[2];
#pragma unroll
    for (int it = 0; it < 4; ++it) rq[it] = blk[q * 4 + it];
#pragma unroll
    for (int it = 0; it < 2; ++it) sq[it] = sblk[q * 2 + it];

    float acc = 0.0f;
#pragma unroll
    for (int rr = 0; rr < 8; ++rr) {
        uint4 qq = rq[rr >> 1];
        unsigned w0 = (rr & 1) ? qq.z : qq.x;
        unsigned w1 = (rr & 1) ? qq.w : qq.y;
        int4 sv = sq[rr >> 2];
        int s2 = (rr & 3) == 0 ? sv.x : (rr & 3) == 1 ? sv.y
               : (rr & 3) == 2 ? sv.z : sv.w;
        h2 kxy = __builtin_bit_cast(h2, w0);
        h2 kzf = __builtin_bit_cast(h2, w1);
        float cosv = fdot2(kxy, ne_xy, fdot2(kzf, ne_z0, 0.0f));
        cosv = fminf(fmaxf(cosv, -1.0f), 1.0f);
        // g(cos): cos in [-1,1] -> u in [0,6]; trunc == floor (u >= 0)
        float u = (cosv + 1.0f) * 3.0f;
        int idx = (int)u;
        idx = idx > NINT - 1 ? NINT - 1 : idx;
        float s = cosv - (-1.0f + (2.0f / 6.0f) * (float)idx);
        float4 c = sG[idx];
        float g = c.x + s * (c.y + s * (c.z + s * c.w));
        float fk = (float)kzf.y;
        float term = (s2 != de) ? fk * g : 0.0f;
        acc += term;
    }

    // reduce the 4-lane group (xor 1,2 stay within the group)
    acc += __shfl_xor(acc, 1, 64);
    acc += __shfl_xor(acc, 2, 64);
    if (q == 0) out[e] = fe * acc;
}

extern "C" void kernel_launch(void* const* d_in, const int* in_sizes, int n_in,
                              void* d_out, int out_size, void* d_ws, size_t ws_size,
                              hipStream_t stream) {
    const float* r   = (const float*)d_in[0];
    const float* fc  = (const float*)d_in[1];
    const float* gc  = (const float*)d_in[2];
    const int* src   = (const int*)d_in[3];
    float* out = (float*)d_out;
    int E = in_sizes[3];

    uint2* uf = (uint2*)d_ws;  // E * 8 bytes

    int threads = 256;
    int blocks1 = (E + threads - 1) / threads;
    edge_kernel<<<blocks1, threads, 0, stream>>>(r, fc, uf, E);

    long long T2 = (long long)E * 4;   // 4 lanes per edge
    int blocks2 = (int)((T2 + threads - 1) / threads);
    triplet_kernel<<<blocks2, threads, 0, stream>>>(uf, gc, src, out, E);
}